// Round 11
// baseline (1700.525 us; speedup 1.0000x reference)
//
#include <hip/hip_runtime.h>
#include <hip/hip_fp16.h>

typedef _Float16 f16;
typedef __attribute__((ext_vector_type(8))) _Float16 f16x8;
typedef __attribute__((ext_vector_type(4))) _Float16 f16x4;
typedef __attribute__((ext_vector_type(4))) float f32x4;
typedef __attribute__((ext_vector_type(4))) float float4v;
typedef long long i64;

// Shapes: x[512,256,256], carry0[256,256], Wi[256,768], bi[768],
//         Wh[256,768], bhn[256], Wo[256,16], bo[16] -> out[512,256,16] f32
//
// gx layout (scan-fragment order), f16, SCALED x128:
//   vecidx = ((t*16 + blk)*8 + w8)*6 + (gate*2 + nt2); elem = vecidx*256+lane*4+j
// Scan scaling: h fp8 x16; Wh fp8 x8; Wo fp8 x256; gx f16 x128.
//
// Fused producer-consumer: blocks 0..15 run the scan; blocks 16.. run the
// gx GEMM (4 independent 256-thread groups per block, one 128x128 tile each).
// GEMM signals flags[by]+=1 (RELEASE/agent) after its tile's stores; scan
// confirms flags[t*2+bhf]==6 (ACQUIRE) two steps ahead of consumption.

static __device__ __forceinline__ float sigm_s(float x) {  // sigmoid(x/128)
  return __builtin_amdgcn_rcpf(1.0f + __expf(-0.0078125f * x));
}
static __device__ __forceinline__ float tanh_s(float x) {  // tanh(x/128)
  float e = __expf(0.015625f * x);
  return 1.0f - 2.0f * __builtin_amdgcn_rcpf(e + 1.0f);
}

// ---------------- K0: transpose+convert Wi -> WiT[768][256] f16 -------------
__global__ void k_prep_wit(const float* __restrict__ Wi, f16* __restrict__ WiT) {
  int n = blockIdx.x;
  int k = threadIdx.x;
  WiT[n * 256 + k] = (f16)Wi[(size_t)k * 768 + n];
}

// ---------------- fused GEMM + scan ----------------------------------------
__global__ __launch_bounds__(1024) void k_fused(
    const float* __restrict__ x, const f16* __restrict__ WiT,
    const float* __restrict__ bi, const float* __restrict__ carry0,
    const float* __restrict__ Wh, const float* __restrict__ bhn,
    f16* __restrict__ gx, const float* __restrict__ Wo,
    const float* __restrict__ bo, float* __restrict__ out,
    unsigned int* __restrict__ flags) {
  // scan LDS
  __shared__ char ha[2 * 4096];  // 2 slots x 8 frames x 512B fp8 A-frags
  __shared__ char wofs[4096];    // 8 frames x 512B fp8 Wo B-frags
  // gemm LDS (4 groups) -- combined 140KB forces 1 block/CU (no contention)
  __shared__ f16 As[4][128 * 64];
  __shared__ f16 Bs[4][128 * 64];

  const int tid = threadIdx.x;

  if (blockIdx.x >= 16) {
    // ================= GEMM role: 4 groups x 256 threads ==================
    const int group = tid >> 8;
    const int tid2 = tid & 255;
    const int lane = tid2 & 63;
    const int wave = tid2 >> 6;  // 0..3 within group
    const int wm = wave >> 1, wn = wave & 1;
    const int tile = (blockIdx.x - 16) * 4 + group;  // 0..6143
    const int bx = tile % 6;
    const int by = tile / 6;
    const int m0 = by * 128;
    const int n0 = bx * 128;
    f16* as = As[group];
    f16* bs = Bs[group];

    f32x4 acc[4][4] = {};

    for (int ks = 0; ks < 4; ++ks) {
      const int k0 = ks * 64;
#pragma unroll
      for (int i = 0; i < 8; ++i) {
        int c = i * 256 + tid2;
        int row = c >> 4, cx = c & 15;
        float4v v = *reinterpret_cast<const float4v*>(
            x + (size_t)(m0 + row) * 256 + k0 + cx * 4);
        f16x4 hv;
        hv[0] = (f16)v[0]; hv[1] = (f16)v[1]; hv[2] = (f16)v[2]; hv[3] = (f16)v[3];
        int boff = row * 128 + ((cx * 8) ^ ((row & 7) << 4));
        *reinterpret_cast<f16x4*>(reinterpret_cast<char*>(as) + boff) = hv;
      }
#pragma unroll
      for (int i = 0; i < 4; ++i) {
        int c = i * 256 + tid2;
        int n = c >> 3, cx = c & 7;
        f16x8 v = *reinterpret_cast<const f16x8*>(
            WiT + (size_t)(n0 + n) * 256 + k0 + cx * 8);
        int boff = n * 128 + ((cx * 16) ^ ((n & 7) << 4));
        *reinterpret_cast<f16x8*>(reinterpret_cast<char*>(bs) + boff) = v;
      }
      __syncthreads();
#pragma unroll
      for (int kt = 0; kt < 2; ++kt) {
        const int kb = kt * 64 + ((lane >> 4) << 4);
        f16x8 a[4], b[4];
#pragma unroll
        for (int mt = 0; mt < 4; ++mt) {
          int r = wm * 64 + mt * 16 + (lane & 15);
          a[mt] = *reinterpret_cast<const f16x8*>(
              reinterpret_cast<const char*>(as) + r * 128 + (kb ^ ((r & 7) << 4)));
        }
#pragma unroll
        for (int nt = 0; nt < 4; ++nt) {
          int r = wn * 64 + nt * 16 + (lane & 15);
          b[nt] = *reinterpret_cast<const f16x8*>(
              reinterpret_cast<const char*>(bs) + r * 128 + (kb ^ ((r & 7) << 4)));
        }
#pragma unroll
        for (int mt = 0; mt < 4; ++mt)
#pragma unroll
          for (int nt = 0; nt < 4; ++nt)
            acc[mt][nt] = __builtin_amdgcn_mfma_f32_16x16x32_f16(
                a[mt], b[nt], acc[mt][nt], 0, 0, 0);
      }
      __syncthreads();
    }
    const int t_  = by >> 1;
    const int bhf = by & 1;
    const int gg  = bx >> 1;
    const int xh  = bx & 1;
    float biv[4];
#pragma unroll
    for (int nt = 0; nt < 4; ++nt)
      biv[nt] = bi[n0 + wn * 64 + nt * 16 + (lane & 15)];
#pragma unroll
    for (int mt = 0; mt < 4; ++mt) {
      const int blk = bhf * 8 + wm * 4 + mt;
#pragma unroll
      for (int nt = 0; nt < 4; ++nt) {
        const int w = xh * 4 + wn * 2 + (nt >> 1);
        const int vecidx = ((t_ * 16 + blk) * 8 + w) * 6 + gg * 2 + (nt & 1);
        f16x4 hv;
#pragma unroll
        for (int r = 0; r < 4; ++r)
          hv[r] = (f16)((acc[mt][nt][r] + biv[nt]) * 128.0f);
        *reinterpret_cast<f16x4*>(gx + (size_t)vecidx * 256 + lane * 4) = hv;
      }
    }
    // all groups' stores drained (syncthreads waits vmcnt), then release
    __syncthreads();
    if (tid2 == 0)
      __hip_atomic_fetch_add(flags + by, 1u, __ATOMIC_RELEASE,
                             __HIP_MEMORY_SCOPE_AGENT);
    return;
  }

  // ===================== scan role (R10 structure) ========================
  const int lane = tid & 63;
  const int wave = tid >> 6;  // 0..15
  const int l15 = lane & 15, l4 = lane >> 4;
  const int r0 = blockIdx.x * 16;
  const int bhf = blockIdx.x >> 3;
  const unsigned int* flg = flags;

  // 3 Wh gates for own 16 cols -> fp8 register B-frags (48 VGPRs), x8 scale
  i64 whf[3][8];
#pragma unroll
  for (int g = 0; g < 3; ++g) {
    const int col = g * 256 + wave * 16 + l15;
#pragma unroll
    for (int kt = 0; kt < 8; ++kt) {
      float w[8];
#pragma unroll
      for (int e = 0; e < 8; ++e)
        w[e] = Wh[(size_t)(kt * 32 + l4 * 8 + e) * 768 + col] * 8.0f;
      int lo = 0, hi = 0;
      lo = __builtin_amdgcn_cvt_pk_fp8_f32(w[0], w[1], lo, false);
      lo = __builtin_amdgcn_cvt_pk_fp8_f32(w[2], w[3], lo, true);
      hi = __builtin_amdgcn_cvt_pk_fp8_f32(w[4], w[5], hi, false);
      hi = __builtin_amdgcn_cvt_pk_fp8_f32(w[6], w[7], hi, true);
      whf[g][kt] = (i64)(unsigned int)lo | ((i64)(unsigned int)hi << 32);
    }
  }
  // Wo -> fp8 LDS B-frags (x256); waves 0-7 build frame kt=wave
  if (wave < 8) {
    float w[8];
#pragma unroll
    for (int e = 0; e < 8; ++e)
      w[e] = Wo[(wave * 32 + l4 * 8 + e) * 16 + l15] * 256.0f;
    int lo = 0, hi = 0;
    lo = __builtin_amdgcn_cvt_pk_fp8_f32(w[0], w[1], lo, false);
    lo = __builtin_amdgcn_cvt_pk_fp8_f32(w[2], w[3], lo, true);
    hi = __builtin_amdgcn_cvt_pk_fp8_f32(w[4], w[5], hi, false);
    hi = __builtin_amdgcn_cvt_pk_fp8_f32(w[6], w[7], hi, true);
    *reinterpret_cast<int*>(wofs + wave * 512 + lane * 8) = lo;
    *reinterpret_cast<int*>(wofs + wave * 512 + lane * 8 + 4) = hi;
  }
  const float bh128 = 128.0f * bhn[wave * 16 + l15];
  const float bov = bo[l15];

  const int fme = wave >> 1;
  const int sme = (wave & 1) * 2 + (l15 >> 3);
  const int e8 = l15 & 7;
  float hcur[4];
  {
    float hs[4];
#pragma unroll
    for (int j = 0; j < 4; ++j) {
      float h = carry0[(size_t)(r0 + l4 * 4 + j) * 256 + wave * 16 + l15];
      hcur[j] = h;
      hs[j] = h * 16.0f;
    }
    int pk = 0;
    pk = __builtin_amdgcn_cvt_pk_fp8_f32(hs[0], hs[1], pk, false);
    pk = __builtin_amdgcn_cvt_pk_fp8_f32(hs[2], hs[3], pk, true);
#pragma unroll
    for (int j = 0; j < 4; ++j) {
      const int g = sme * 16 + l4 * 4 + j;
      const int p = g ^ (g >> 3);
      ha[fme * 512 + p * 8 + e8] = (char)(pk >> (8 * j));
    }
  }
  __syncthreads();

  // wait for gx[0] and gx[1] (flags[t*2+bhf]==6)
  while (__hip_atomic_load(flg + 0 * 2 + bhf, __ATOMIC_ACQUIRE,
                           __HIP_MEMORY_SCOPE_AGENT) < 6u)
    __builtin_amdgcn_s_sleep(2);
  while (__hip_atomic_load(flg + 1 * 2 + bhf, __ATOMIC_ACQUIRE,
                           __HIP_MEMORY_SCOPE_AGENT) < 6u)
    __builtin_amdgcn_s_sleep(2);

  const f16* gp0 = gx + (((size_t)blockIdx.x * 8 + (wave >> 1)) * 6 +
                         (size_t)(wave & 1)) * 256 + (size_t)lane * 4;
  const int rdoff = (lane ^ (lane >> 3)) * 8;

  f16x4 gva[3], gvb[3];
#pragma unroll
  for (int g = 0; g < 3; ++g)
    gva[g] = *reinterpret_cast<const f16x4*>(gp0 + g * 512);

  auto step = [&](int cur, int nxt, f16x4 (&gv)[3], f16x4 (&gvn)[3],
                  const f16* gpn, int tt) {
    // early-issue the readiness check for t+2 (tested at step end)
    unsigned int fv = 6u;
    if (tt + 2 <= 511)
      fv = __hip_atomic_load(flg + (tt + 2) * 2 + bhf, __ATOMIC_ACQUIRE,
                             __HIP_MEMORY_SCOPE_AGENT);
    // prefetch NEXT step's gx (flag confirmed two steps ago)
#pragma unroll
    for (int g = 0; g < 3; ++g)
      gvn[g] = *reinterpret_cast<const f16x4*>(gpn + g * 512);

    f32x4 acc0, acc1, acc2;
#pragma unroll
    for (int j = 0; j < 4; ++j) {
      acc0[j] = (float)gv[0][j];
      acc1[j] = (float)gv[1][j];
      acc2[j] = bh128;
    }
#pragma unroll
    for (int kt = 0; kt < 8; ++kt) {
      i64 a = *reinterpret_cast<const i64*>(ha + cur + kt * 512 + rdoff);
      acc0 = __builtin_amdgcn_mfma_f32_16x16x32_fp8_fp8(a, whf[0][kt], acc0, 0, 0, 0);
      acc1 = __builtin_amdgcn_mfma_f32_16x16x32_fp8_fp8(a, whf[1][kt], acc1, 0, 0, 0);
      acc2 = __builtin_amdgcn_mfma_f32_16x16x32_fp8_fp8(a, whf[2][kt], acc2, 0, 0, 0);
    }

    // fused head on wave 0: out[tt-1] = h_tt @ Wo (acc scale 16*256=4096)
    if (wave == 0) {
      f32x4 aco = {};
#pragma unroll
      for (int kt = 0; kt < 8; ++kt) {
        i64 ah = *reinterpret_cast<const i64*>(ha + cur + kt * 512 + rdoff);
        i64 wb = *reinterpret_cast<const i64*>(wofs + kt * 512 + lane * 8);
        aco = __builtin_amdgcn_mfma_f32_16x16x32_fp8_fp8(ah, wb, aco, 0, 0, 0);
      }
      if (tt > 0) {
#pragma unroll
        for (int r = 0; r < 4; ++r) {
          float y = fmaf(aco[r], 2.44140625e-4f, bov);
          if (l15 >= 8) y = __expf(fminf(fmaxf(y, -20.0f), 2.0f));
          out[((size_t)(tt - 1) * 256 + r0 + l4 * 4 + r) * 16 + l15] = y;
        }
      }
    }

    // elementwise GRU + fp8 A-frag write of h_{t+1}
    {
      float hs[4];
#pragma unroll
      for (int j = 0; j < 4; ++j) {
        float rg = sigm_s(acc0[j]);
        float zg = sigm_s(acc1[j]);
        float ng = tanh_s((float)gv[2][j] + rg * acc2[j]);
        float h = ng + zg * (hcur[j] - ng);
        hcur[j] = h;
        hs[j] = h * 16.0f;
      }
      int pk = 0;
      pk = __builtin_amdgcn_cvt_pk_fp8_f32(hs[0], hs[1], pk, false);
      pk = __builtin_amdgcn_cvt_pk_fp8_f32(hs[2], hs[3], pk, true);
#pragma unroll
      for (int j = 0; j < 4; ++j) {
        const int g = sme * 16 + l4 * 4 + j;
        const int p = g ^ (g >> 3);
        ha[nxt + fme * 512 + p * 8 + e8] = (char)(pk >> (8 * j));
      }
    }
    // late-test the t+2 readiness (normally already satisfied)
    if (tt + 2 <= 511) {
      while (fv < 6u) {
        __builtin_amdgcn_s_sleep(2);
        fv = __hip_atomic_load(flg + (tt + 2) * 2 + bhf, __ATOMIC_ACQUIRE,
                               __HIP_MEMORY_SCOPE_AGENT);
      }
    }
    asm volatile("s_waitcnt lgkmcnt(0)\n\ts_barrier" ::: "memory");
  };

  for (int t = 0; t < 512; t += 2) {
    const f16* gp1 = gp0 + (size_t)(t + 1) * 196608;
    const f16* gp2 = gp0 + (size_t)(t + 2 <= 511 ? t + 2 : 511) * 196608;
    step(0, 4096, gva, gvb, gp1, t);
    step(4096, 0, gvb, gva, gp2, t + 1);
  }

  // final head: out[511] = h_512 @ Wo (h_512 in slot 0)
  if (wave == 0) {
    f32x4 aco = {};
#pragma unroll
    for (int kt = 0; kt < 8; ++kt) {
      i64 ah = *reinterpret_cast<const i64*>(ha + kt * 512 + rdoff);
      i64 wb = *reinterpret_cast<const i64*>(wofs + kt * 512 + lane * 8);
      aco = __builtin_amdgcn_mfma_f32_16x16x32_fp8_fp8(ah, wb, aco, 0, 0, 0);
    }
#pragma unroll
    for (int r = 0; r < 4; ++r) {
      float y = fmaf(aco[r], 2.44140625e-4f, bov);
      if (l15 >= 8) y = __expf(fminf(fmaxf(y, -20.0f), 2.0f));
      out[((size_t)511 * 256 + r0 + l4 * 4 + r) * 16 + l15] = y;
    }
  }
}

extern "C" void kernel_launch(void* const* d_in, const int* in_sizes, int n_in,
                              void* d_out, int out_size, void* d_ws, size_t ws_size,
                              hipStream_t stream) {
  const float* x      = (const float*)d_in[0];
  const float* carry0 = (const float*)d_in[1];
  const float* Wi     = (const float*)d_in[2];
  const float* bi     = (const float*)d_in[3];
  const float* Wh     = (const float*)d_in[4];
  const float* bhn    = (const float*)d_in[5];
  const float* Wo     = (const float*)d_in[6];
  const float* bo     = (const float*)d_in[7];
  float* out = (float*)d_out;

  f16* gx  = (f16*)d_ws;                       // 512*256*768 f16 = 192 MiB
  f16* WiT = gx + (size_t)512 * 256 * 768;     // 768*256 f16 = 384 KiB
  unsigned int* flags = (unsigned int*)(WiT + (size_t)768 * 256);  // 1024 u32

  hipMemsetAsync(flags, 0, 1024 * sizeof(unsigned int), stream);
  k_prep_wit<<<dim3(768), dim3(256), 0, stream>>>(Wi, WiT);
  k_fused<<<dim3(16 + 1536), dim3(1024), 0, stream>>>(
      x, WiT, bi, carry0, Wh, bhn, gx, Wo, bo, out, flags);
}

// Round 12
// 920.841 us; speedup vs baseline: 1.8467x; 1.8467x over previous
//
#include <hip/hip_runtime.h>
#include <hip/hip_fp16.h>

typedef _Float16 f16;
typedef __attribute__((ext_vector_type(8))) _Float16 f16x8;
typedef __attribute__((ext_vector_type(4))) _Float16 f16x4;
typedef __attribute__((ext_vector_type(4))) float f32x4;
typedef __attribute__((ext_vector_type(4))) float float4v;
typedef __attribute__((ext_vector_type(4))) int i32x4;

// Shapes: x[512,256,256], carry0[256,256], Wi[256,768], bi[768],
//         Wh[256,768], bhn[256], Wo[256,16], bo[16] -> out[512,256,16] f32
//
// gx layout (scan-fragment order, produced by K1), f16, SCALED x128:
//   vecidx = ((t*16 + blk)*8 + w8)*6 + (gate*2 + nt2); elem = vecidx*256+lane*4+j
// K2 (16 waves of 16 cols): w8 = wave>>1, nt2 = wave&1.
//
// Scan numerics (int8 MFMA, K=64): h int8 as round(127*h); Wh int8 as
// round(256*Wh); Wo int8 as round(16384*Wo); gx f16 as 128*(xWi+bi).
// preact*128 = gx + acc*(128/(127*256)); head y = acc/(127*16384).

#define CS 0.0039370079f        // 128/32512
#define CHEAD 4.805919e-7f      // 1/(127*16384)
#define FMAGIC 12582912.0f      // 1.5*2^23 (round-to-nearest-int trick)
#define IMAGIC 1262485504       // bit pattern of FMAGIC

static __device__ __forceinline__ float sigm_s(float x) {  // sigmoid(x/128)
  return __builtin_amdgcn_rcpf(1.0f + __expf(-0.0078125f * x));
}
static __device__ __forceinline__ float tanh_s(float x) {  // tanh(x/128)
  float e = __expf(0.015625f * x);
  return 1.0f - 2.0f * __builtin_amdgcn_rcpf(e + 1.0f);
}

// ---------------- K0: transpose+convert Wi -> WiT[768][256] f16 -------------
__global__ void k_prep_wit(const float* __restrict__ Wi, f16* __restrict__ WiT) {
  int n = blockIdx.x;
  int k = threadIdx.x;
  WiT[n * 256 + k] = (f16)Wi[(size_t)k * 768 + n];
}

// ---------------- K1: gx = 128*(x @ Wi + bi)  (fp16 MFMA, 128x128 tile) -----
__global__ __launch_bounds__(256, 4) void k_gemm_gx(
    const float* __restrict__ x, const f16* __restrict__ WiT,
    const float* __restrict__ bi, f16* __restrict__ gx) {
  __shared__ f16 As[128 * 64];
  __shared__ f16 Bs[128 * 64];
  const int tid = threadIdx.x;
  const int lane = tid & 63;
  const int wave = tid >> 6;
  const int wm = wave >> 1, wn = wave & 1;
  const int m0 = blockIdx.y * 128;
  const int n0 = blockIdx.x * 128;

  f32x4 acc[4][4] = {};

  for (int ks = 0; ks < 4; ++ks) {
    const int k0 = ks * 64;
#pragma unroll
    for (int i = 0; i < 8; ++i) {
      int c = i * 256 + tid;
      int row = c >> 4, cx = c & 15;
      float4v v = *reinterpret_cast<const float4v*>(
          x + (size_t)(m0 + row) * 256 + k0 + cx * 4);
      f16x4 hv;
      hv[0] = (f16)v[0]; hv[1] = (f16)v[1]; hv[2] = (f16)v[2]; hv[3] = (f16)v[3];
      int boff = row * 128 + ((cx * 8) ^ ((row & 7) << 4));
      *reinterpret_cast<f16x4*>(reinterpret_cast<char*>(As) + boff) = hv;
    }
#pragma unroll
    for (int i = 0; i < 4; ++i) {
      int c = i * 256 + tid;
      int n = c >> 3, cx = c & 7;
      f16x8 v = *reinterpret_cast<const f16x8*>(
          WiT + (size_t)(n0 + n) * 256 + k0 + cx * 8);
      int boff = n * 128 + ((cx * 16) ^ ((n & 7) << 4));
      *reinterpret_cast<f16x8*>(reinterpret_cast<char*>(Bs) + boff) = v;
    }
    __syncthreads();
#pragma unroll
    for (int kt = 0; kt < 2; ++kt) {
      const int kb = kt * 64 + ((lane >> 4) << 4);
      f16x8 a[4], b[4];
#pragma unroll
      for (int mt = 0; mt < 4; ++mt) {
        int r = wm * 64 + mt * 16 + (lane & 15);
        a[mt] = *reinterpret_cast<const f16x8*>(
            reinterpret_cast<const char*>(As) + r * 128 + (kb ^ ((r & 7) << 4)));
      }
#pragma unroll
      for (int nt = 0; nt < 4; ++nt) {
        int r = wn * 64 + nt * 16 + (lane & 15);
        b[nt] = *reinterpret_cast<const f16x8*>(
            reinterpret_cast<const char*>(Bs) + r * 128 + (kb ^ ((r & 7) << 4)));
      }
#pragma unroll
      for (int mt = 0; mt < 4; ++mt)
#pragma unroll
        for (int nt = 0; nt < 4; ++nt)
          acc[mt][nt] = __builtin_amdgcn_mfma_f32_16x16x32_f16(
              a[mt], b[nt], acc[mt][nt], 0, 0, 0);
    }
    __syncthreads();
  }
  const int t_  = blockIdx.y >> 1;
  const int bhf = blockIdx.y & 1;
  const int gg  = blockIdx.x >> 1;
  const int xh  = blockIdx.x & 1;
  float biv[4];
#pragma unroll
  for (int nt = 0; nt < 4; ++nt) biv[nt] = bi[n0 + wn * 64 + nt * 16 + (lane & 15)];
#pragma unroll
  for (int mt = 0; mt < 4; ++mt) {
    const int blk = bhf * 8 + wm * 4 + mt;
#pragma unroll
    for (int nt = 0; nt < 4; ++nt) {
      const int w = xh * 4 + wn * 2 + (nt >> 1);
      const int vecidx = ((t_ * 16 + blk) * 8 + w) * 6 + gg * 2 + (nt & 1);
      f16x4 hv;
#pragma unroll
      for (int r = 0; r < 4; ++r)
        hv[r] = (f16)((acc[mt][nt][r] + biv[nt]) * 128.0f);
      *reinterpret_cast<f16x4*>(gx + (size_t)vecidx * 256 + lane * 4) = hv;
    }
  }
}

// ---------------- K2: int8 GRU scan, 16 blocks x 16 waves (4/SIMD) ----------
// Wave owns 16 H-cols; Wh int8 B-frags in VGPRs (48 regs, K=64 per frag).
// h int8 A-frags in an 8-slot LDS ring (4 frames x 1024B per slot; read b128
// lane-linear conflict-free; write 4 byte-stores/thread). Heads batched every
// 8 steps (waves 0-7, one tau each) from the ring using int8 Wo in LDS.
__global__ __launch_bounds__(1024) void k_scan(
    const float* __restrict__ carry0, const float* __restrict__ Wh,
    const float* __restrict__ bhn, const f16* __restrict__ gxL,
    const float* __restrict__ Wo, const float* __restrict__ bo,
    float* __restrict__ out) {
  __shared__ __align__(16) char ha[8 * 4096];   // 32 KB: h ring, 8 slots
  __shared__ __align__(16) char wofs[4 * 1024]; // 4 KB: Wo int8 B-frags
  const int tid = threadIdx.x;
  const int lane = tid & 63;
  const int wave = tid >> 6;  // 0..15
  const int l15 = lane & 15, l4 = lane >> 4;
  const int r0 = blockIdx.x * 16;

  // 3 Wh gates for own 16 cols -> int8 register B-frags (48 VGPRs), x256
  // B layout: lane holds (n=lane&15, k = kt*64 + (lane>>4)*16 + e), e=0..15,
  // byte e of the 16B frag (little-endian within each i32 word).
  i32x4 whq[3][4];
#pragma unroll
  for (int g = 0; g < 3; ++g) {
    const int col = g * 256 + wave * 16 + l15;
#pragma unroll
    for (int kt = 0; kt < 4; ++kt) {
      int wd[4];
#pragma unroll
      for (int w = 0; w < 4; ++w) {
        int b = 0;
#pragma unroll
        for (int by = 0; by < 4; ++by) {
          const int e = w * 4 + by;
          int q = (int)rintf(Wh[(size_t)(kt * 64 + l4 * 16 + e) * 768 + col] *
                             256.0f);
          b |= (q & 255) << (8 * by);
        }
        wd[w] = b;
      }
      whq[g][kt] = (i32x4){wd[0], wd[1], wd[2], wd[3]};
    }
  }
  // Wo -> int8 LDS B-frags (x16384); waves 0-3 build frame kt=wave
  if (wave < 4) {
    int wd[4];
#pragma unroll
    for (int w = 0; w < 4; ++w) {
      int b = 0;
#pragma unroll
      for (int by = 0; by < 4; ++by) {
        const int e = w * 4 + by;
        int q = (int)rintf(Wo[(wave * 64 + l4 * 16 + e) * 16 + l15] * 16384.0f);
        b |= (q & 255) << (8 * by);
      }
      wd[w] = b;
    }
    *reinterpret_cast<i32x4*>(wofs + wave * 1024 + lane * 16) =
        (i32x4){wd[0], wd[1], wd[2], wd[3]};
  }
  const float bh128 = 128.0f * bhn[wave * 16 + l15];
  const float bov = bo[l15];

  // h write address: frame = wave>>2, granule = (wave&3)*16 + l4*4 + j, byte l15
  const int wrbase = (wave >> 2) * 1024 + ((wave & 3) * 16 + l4 * 4) * 16 + l15;

  // init h_0 -> hcur + int8 A-frags in slot 0
  float hcur[4];
#pragma unroll
  for (int j = 0; j < 4; ++j) {
    float h = carry0[(size_t)(r0 + l4 * 4 + j) * 256 + wave * 16 + l15];
    hcur[j] = h;
    float m = fmaf(h, 127.0f, FMAGIC);
    int hq = __builtin_bit_cast(int, m) - IMAGIC;
    ha[wrbase + j * 16] = (char)hq;
  }
  __syncthreads();

  const f16* gp0 = gxL + (((size_t)blockIdx.x * 8 + (wave >> 1)) * 6 +
                          (size_t)(wave & 1)) * 256 + (size_t)lane * 4;

  // head for timestep tau (h_tau in ring slot tau&7) -> out[tau-1]
  auto head_tau = [&](int tau) {
    const int sbase = (tau & 7) * 4096;
    i32x4 aco = {};
#pragma unroll
    for (int kt = 0; kt < 4; ++kt) {
      i32x4 ah = *reinterpret_cast<const i32x4*>(ha + sbase + kt * 1024 + lane * 16);
      i32x4 wb = *reinterpret_cast<const i32x4*>(wofs + kt * 1024 + lane * 16);
      aco = __builtin_amdgcn_mfma_i32_16x16x64_i8(ah, wb, aco, 0, 0, 0);
    }
#pragma unroll
    for (int r = 0; r < 4; ++r) {
      float y = fmaf((float)aco[r], CHEAD, bov);
      if (l15 >= 8) y = __expf(fminf(fmaxf(y, -20.0f), 2.0f));
      out[((size_t)(tau - 1) * 256 + r0 + l4 * 4 + r) * 16 + l15] = y;
    }
  };

  f16x4 gva[3], gvb[3];
#pragma unroll
  for (int g = 0; g < 3; ++g)
    gva[g] = *reinterpret_cast<const f16x4*>(gp0 + g * 512);

  auto step = [&](int cur, int nxt, f16x4 (&gv)[3], f16x4 (&gvn)[3],
                  const f16* gpn, int tt) {
    // batched heads every 8 steps: taus tt-7..tt, one per wave 0..7. The
    // barrier keeps this step's slot-(tt+1) writes off tau tt-7's reads.
    if ((tt & 7) == 0 && tt > 0) {
      if (wave < 8) head_tau(tt - 7 + wave);
      asm volatile("s_waitcnt lgkmcnt(0)\n\ts_barrier" ::: "memory");
    }
    // prefetch NEXT step's gx (in flight across the light barrier)
#pragma unroll
    for (int g = 0; g < 3; ++g)
      gvn[g] = *reinterpret_cast<const f16x4*>(gpn + g * 512);

    i32x4 acc0 = {}, acc1 = {}, acc2 = {};
#pragma unroll
    for (int kt = 0; kt < 4; ++kt) {
      i32x4 a = *reinterpret_cast<const i32x4*>(ha + cur + kt * 1024 + lane * 16);
      acc0 = __builtin_amdgcn_mfma_i32_16x16x64_i8(a, whq[0][kt], acc0, 0, 0, 0);
      acc1 = __builtin_amdgcn_mfma_i32_16x16x64_i8(a, whq[1][kt], acc1, 0, 0, 0);
      acc2 = __builtin_amdgcn_mfma_i32_16x16x64_i8(a, whq[2][kt], acc2, 0, 0, 0);
    }

    // elementwise GRU + int8 A-frag write of h_{t+1}
#pragma unroll
    for (int j = 0; j < 4; ++j) {
      float pr = fmaf((float)acc0[j], CS, (float)gv[0][j]);
      float pz = fmaf((float)acc1[j], CS, (float)gv[1][j]);
      float pnh = fmaf((float)acc2[j], CS, bh128);
      float rg = sigm_s(pr);
      float zg = sigm_s(pz);
      float ng = tanh_s(fmaf(rg, pnh, (float)gv[2][j]));
      float h = ng + zg * (hcur[j] - ng);
      hcur[j] = h;
      float m = fmaf(h, 127.0f, FMAGIC);
      int hq = __builtin_bit_cast(int, m) - IMAGIC;
      ha[nxt + wrbase + j * 16] = (char)hq;
    }
    // light barrier: order LDS h-handoff only (vmcnt stays in flight)
    asm volatile("s_waitcnt lgkmcnt(0)\n\ts_barrier" ::: "memory");
  };

  for (int t = 0; t < 512; t += 2) {
    const f16* gp1 = gp0 + (size_t)(t + 1) * 196608;
    const f16* gp2 = gp0 + (size_t)(t + 2 <= 511 ? t + 2 : 511) * 196608;
    step((t & 7) * 4096, ((t + 1) & 7) * 4096, gva, gvb, gp1, t);
    step(((t + 1) & 7) * 4096, ((t + 2) & 7) * 4096, gvb, gva, gp2, t + 1);
  }

  // final heads: taus 505..512 (slots 1..7,0 — all intact)
  if (wave < 8) head_tau(505 + wave);
}

extern "C" void kernel_launch(void* const* d_in, const int* in_sizes, int n_in,
                              void* d_out, int out_size, void* d_ws, size_t ws_size,
                              hipStream_t stream) {
  const float* x      = (const float*)d_in[0];
  const float* carry0 = (const float*)d_in[1];
  const float* Wi     = (const float*)d_in[2];
  const float* bi     = (const float*)d_in[3];
  const float* Wh     = (const float*)d_in[4];
  const float* bhn    = (const float*)d_in[5];
  const float* Wo     = (const float*)d_in[6];
  const float* bo     = (const float*)d_in[7];
  float* out = (float*)d_out;

  f16* gx  = (f16*)d_ws;                       // 512*256*768 f16 = 192 MiB
  f16* WiT = gx + (size_t)512 * 256 * 768;     // 768*256 f16

  k_prep_wit<<<dim3(768), dim3(256), 0, stream>>>(Wi, WiT);
  k_gemm_gx<<<dim3(6, 1024), dim3(256), 0, stream>>>(x, WiT, bi, gx);
  k_scan<<<dim3(16), dim3(1024), 0, stream>>>(carry0, Wh, bhn, gx, Wo, bo, out);
}

// Round 13
// 799.582 us; speedup vs baseline: 2.1268x; 1.1517x over previous
//
#include <hip/hip_runtime.h>
#include <hip/hip_fp16.h>

typedef _Float16 f16;
typedef __attribute__((ext_vector_type(8))) _Float16 f16x8;
typedef __attribute__((ext_vector_type(4))) _Float16 f16x4;
typedef __attribute__((ext_vector_type(4))) float f32x4;
typedef __attribute__((ext_vector_type(4))) float float4v;
typedef __attribute__((ext_vector_type(4))) int i32x4;

typedef __attribute__((address_space(3))) unsigned int lds_u32;
typedef const __attribute__((address_space(1))) unsigned int glb_u32;

// Shapes: x[512,256,256], carry0[256,256], Wi[256,768], bi[768],
//         Wh[256,768], bhn[256], Wo[256,16], bo[16] -> out[512,256,16] f32
//
// gx layout (scan-fragment order), f16, SCALED x128:
//   vecidx = ((t*16 + blk)*8 + w8)*6 + (gate*2 + nt2); elem = vecidx*256+lane*4+j
// Scan numerics (int8 MFMA, K=64): h int8 x127; Wh int8 x256; Wo int8 x16384;
// gx f16 as 128*(xWi+bi). preact*128 = gx + acc*CS; head y = acc*CHEAD.

#define CS 0.0039370079f        // 128/32512
#define CHEAD 4.805919e-7f      // 1/(127*16384)
#define FMAGIC 12582912.0f      // 1.5*2^23 (round-to-nearest-int trick)
#define IMAGIC 1262485504       // bit pattern of FMAGIC

static __device__ __forceinline__ float sigm_s(float x) {  // sigmoid(x/128)
  return __builtin_amdgcn_rcpf(1.0f + __expf(-0.0078125f * x));
}
static __device__ __forceinline__ float tanh_s(float x) {  // tanh(x/128)
  float e = __expf(0.015625f * x);
  return 1.0f - 2.0f * __builtin_amdgcn_rcpf(e + 1.0f);
}

// ---------------- K0: tiled transpose Wi[256,768] -> WiT[768][256] f16 ------
__global__ void k_prep_wit(const float* __restrict__ Wi, f16* __restrict__ WiT) {
  __shared__ float tile[32][33];
  const int n0 = blockIdx.x * 32;  // 24 blocks over n=768
  const int k0 = blockIdx.y * 32;  // 8 blocks over k=256
  const int tx = threadIdx.x, ty = threadIdx.y;  // (32, 8)
#pragma unroll
  for (int i = 0; i < 4; ++i)
    tile[ty + i * 8][tx] = Wi[(size_t)(k0 + ty + i * 8) * 768 + n0 + tx];
  __syncthreads();
#pragma unroll
  for (int i = 0; i < 4; ++i)
    WiT[(size_t)(n0 + ty + i * 8) * 256 + k0 + tx] = (f16)tile[tx][ty + i * 8];
}

// ---------------- K0b: x f32 -> f16 (memory-bound pass) ---------------------
__global__ __launch_bounds__(256) void k_x16(const float* __restrict__ x,
                                             f16* __restrict__ x16) {
  size_t i = ((size_t)blockIdx.x * 256 + threadIdx.x) * 4;
  const size_t stride = (size_t)gridDim.x * 1024;
  for (; i < (size_t)512 * 256 * 256; i += stride) {
    float4v v = *reinterpret_cast<const float4v*>(x + i);
    f16x4 h;
    h[0] = (f16)v[0]; h[1] = (f16)v[1]; h[2] = (f16)v[2]; h[3] = (f16)v[3];
    *reinterpret_cast<f16x4*>(x16 + i) = h;
  }
}

// ---------------- K1 fast: gx = 128*(x16 @ Wi + bi), global_load_lds --------
// Both A and B staged direct-to-LDS (width 16). XOR swizzle st via
// pre-swizzled GLOBAL source (granule g = cx ^ (row&7)); frag reads use the
// proven kb ^ ((r&7)<<4) formula.
__global__ __launch_bounds__(256, 4) void k_gemm_gx16(
    const f16* __restrict__ x16, const f16* __restrict__ WiT,
    const float* __restrict__ bi, f16* __restrict__ gx) {
  __shared__ f16 As[128 * 64];
  __shared__ f16 Bs[128 * 64];
  const int tid = threadIdx.x;
  const int lane = tid & 63;
  const int wave = tid >> 6;
  const int wm = wave >> 1, wn = wave & 1;
  const int m0 = blockIdx.y * 128;
  const int n0 = blockIdx.x * 128;

  // per-lane pre-swizzled global sources; LDS dst is wave-uniform + lane*16
  const f16* aSrc[4];
  const f16* bSrc[4];
#pragma unroll
  for (int i = 0; i < 4; ++i) {
    const int s = (wave * 4 + i) * 64 + lane;  // linear 16B slot 0..1023
    const int row = s >> 3, cx = s & 7;
    const int g = cx ^ (row & 7);
    aSrc[i] = x16 + (size_t)(m0 + row) * 256 + g * 8;
    bSrc[i] = WiT + (size_t)(n0 + row) * 256 + g * 8;
  }

  f32x4 acc[4][4] = {};

  for (int ks = 0; ks < 4; ++ks) {
#pragma unroll
    for (int i = 0; i < 4; ++i) {
      __builtin_amdgcn_global_load_lds(
          (glb_u32*)(aSrc[i] + ks * 64),
          (lds_u32*)(reinterpret_cast<char*>(As) + (wave * 4 + i) * 1024), 16, 0, 0);
      __builtin_amdgcn_global_load_lds(
          (glb_u32*)(bSrc[i] + ks * 64),
          (lds_u32*)(reinterpret_cast<char*>(Bs) + (wave * 4 + i) * 1024), 16, 0, 0);
    }
    asm volatile("s_waitcnt vmcnt(0)" ::: "memory");
    __syncthreads();
#pragma unroll
    for (int kt = 0; kt < 2; ++kt) {
      const int kb = kt * 64 + ((lane >> 4) << 4);
      f16x8 a[4], b[4];
#pragma unroll
      for (int mt = 0; mt < 4; ++mt) {
        int r = wm * 64 + mt * 16 + (lane & 15);
        a[mt] = *reinterpret_cast<const f16x8*>(
            reinterpret_cast<const char*>(As) + r * 128 + (kb ^ ((r & 7) << 4)));
      }
#pragma unroll
      for (int nt = 0; nt < 4; ++nt) {
        int r = wn * 64 + nt * 16 + (lane & 15);
        b[nt] = *reinterpret_cast<const f16x8*>(
            reinterpret_cast<const char*>(Bs) + r * 128 + (kb ^ ((r & 7) << 4)));
      }
#pragma unroll
      for (int mt = 0; mt < 4; ++mt)
#pragma unroll
        for (int nt = 0; nt < 4; ++nt)
          acc[mt][nt] = __builtin_amdgcn_mfma_f32_16x16x32_f16(
              a[mt], b[nt], acc[mt][nt], 0, 0, 0);
    }
    __syncthreads();
  }
  const int t_  = blockIdx.y >> 1;
  const int bhf = blockIdx.y & 1;
  const int gg  = blockIdx.x >> 1;
  const int xh  = blockIdx.x & 1;
  float biv[4];
#pragma unroll
  for (int nt = 0; nt < 4; ++nt) biv[nt] = bi[n0 + wn * 64 + nt * 16 + (lane & 15)];
#pragma unroll
  for (int mt = 0; mt < 4; ++mt) {
    const int blk = bhf * 8 + wm * 4 + mt;
#pragma unroll
    for (int nt = 0; nt < 4; ++nt) {
      const int w = xh * 4 + wn * 2 + (nt >> 1);
      const int vecidx = ((t_ * 16 + blk) * 8 + w) * 6 + gg * 2 + (nt & 1);
      f16x4 hv;
#pragma unroll
      for (int r = 0; r < 4; ++r)
        hv[r] = (f16)((acc[mt][nt][r] + biv[nt]) * 128.0f);
      *reinterpret_cast<f16x4*>(gx + (size_t)vecidx * 256 + lane * 4) = hv;
    }
  }
}

// ---------------- K1 fallback: gx from f32 x (R12 version, unchanged) -------
__global__ __launch_bounds__(256, 4) void k_gemm_gx(
    const float* __restrict__ x, const f16* __restrict__ WiT,
    const float* __restrict__ bi, f16* __restrict__ gx) {
  __shared__ f16 As[128 * 64];
  __shared__ f16 Bs[128 * 64];
  const int tid = threadIdx.x;
  const int lane = tid & 63;
  const int wave = tid >> 6;
  const int wm = wave >> 1, wn = wave & 1;
  const int m0 = blockIdx.y * 128;
  const int n0 = blockIdx.x * 128;

  f32x4 acc[4][4] = {};

  for (int ks = 0; ks < 4; ++ks) {
    const int k0 = ks * 64;
#pragma unroll
    for (int i = 0; i < 8; ++i) {
      int c = i * 256 + tid;
      int row = c >> 4, cx = c & 15;
      float4v v = *reinterpret_cast<const float4v*>(
          x + (size_t)(m0 + row) * 256 + k0 + cx * 4);
      f16x4 hv;
      hv[0] = (f16)v[0]; hv[1] = (f16)v[1]; hv[2] = (f16)v[2]; hv[3] = (f16)v[3];
      int boff = row * 128 + ((cx * 8) ^ ((row & 7) << 4));
      *reinterpret_cast<f16x4*>(reinterpret_cast<char*>(As) + boff) = hv;
    }
#pragma unroll
    for (int i = 0; i < 4; ++i) {
      int c = i * 256 + tid;
      int n = c >> 3, cx = c & 7;
      f16x8 v = *reinterpret_cast<const f16x8*>(
          WiT + (size_t)(n0 + n) * 256 + k0 + cx * 8);
      int boff = n * 128 + ((cx * 16) ^ ((n & 7) << 4));
      *reinterpret_cast<f16x8*>(reinterpret_cast<char*>(Bs) + boff) = v;
    }
    __syncthreads();
#pragma unroll
    for (int kt = 0; kt < 2; ++kt) {
      const int kb = kt * 64 + ((lane >> 4) << 4);
      f16x8 a[4], b[4];
#pragma unroll
      for (int mt = 0; mt < 4; ++mt) {
        int r = wm * 64 + mt * 16 + (lane & 15);
        a[mt] = *reinterpret_cast<const f16x8*>(
            reinterpret_cast<const char*>(As) + r * 128 + (kb ^ ((r & 7) << 4)));
      }
#pragma unroll
      for (int nt = 0; nt < 4; ++nt) {
        int r = wn * 64 + nt * 16 + (lane & 15);
        b[nt] = *reinterpret_cast<const f16x8*>(
            reinterpret_cast<const char*>(Bs) + r * 128 + (kb ^ ((r & 7) << 4)));
      }
#pragma unroll
      for (int mt = 0; mt < 4; ++mt)
#pragma unroll
        for (int nt = 0; nt < 4; ++nt)
          acc[mt][nt] = __builtin_amdgcn_mfma_f32_16x16x32_f16(
              a[mt], b[nt], acc[mt][nt], 0, 0, 0);
    }
    __syncthreads();
  }
  const int t_  = blockIdx.y >> 1;
  const int bhf = blockIdx.y & 1;
  const int gg  = blockIdx.x >> 1;
  const int xh  = blockIdx.x & 1;
  float biv[4];
#pragma unroll
  for (int nt = 0; nt < 4; ++nt) biv[nt] = bi[n0 + wn * 64 + nt * 16 + (lane & 15)];
#pragma unroll
  for (int mt = 0; mt < 4; ++mt) {
    const int blk = bhf * 8 + wm * 4 + mt;
#pragma unroll
    for (int nt = 0; nt < 4; ++nt) {
      const int w = xh * 4 + wn * 2 + (nt >> 1);
      const int vecidx = ((t_ * 16 + blk) * 8 + w) * 6 + gg * 2 + (nt & 1);
      f16x4 hv;
#pragma unroll
      for (int r = 0; r < 4; ++r)
        hv[r] = (f16)((acc[mt][nt][r] + biv[nt]) * 128.0f);
      *reinterpret_cast<f16x4*>(gx + (size_t)vecidx * 256 + lane * 4) = hv;
    }
  }
}

// ---------------- K2: int8 GRU scan (R12, unchanged) ------------------------
__global__ __launch_bounds__(1024) void k_scan(
    const float* __restrict__ carry0, const float* __restrict__ Wh,
    const float* __restrict__ bhn, const f16* __restrict__ gxL,
    const float* __restrict__ Wo, const float* __restrict__ bo,
    float* __restrict__ out) {
  __shared__ __align__(16) char ha[8 * 4096];   // 32 KB: h ring, 8 slots
  __shared__ __align__(16) char wofs[4 * 1024]; // 4 KB: Wo int8 B-frags
  const int tid = threadIdx.x;
  const int lane = tid & 63;
  const int wave = tid >> 6;  // 0..15
  const int l15 = lane & 15, l4 = lane >> 4;
  const int r0 = blockIdx.x * 16;

  i32x4 whq[3][4];
#pragma unroll
  for (int g = 0; g < 3; ++g) {
    const int col = g * 256 + wave * 16 + l15;
#pragma unroll
    for (int kt = 0; kt < 4; ++kt) {
      int wd[4];
#pragma unroll
      for (int w = 0; w < 4; ++w) {
        int b = 0;
#pragma unroll
        for (int by = 0; by < 4; ++by) {
          const int e = w * 4 + by;
          int q = (int)rintf(Wh[(size_t)(kt * 64 + l4 * 16 + e) * 768 + col] *
                             256.0f);
          b |= (q & 255) << (8 * by);
        }
        wd[w] = b;
      }
      whq[g][kt] = (i32x4){wd[0], wd[1], wd[2], wd[3]};
    }
  }
  if (wave < 4) {
    int wd[4];
#pragma unroll
    for (int w = 0; w < 4; ++w) {
      int b = 0;
#pragma unroll
      for (int by = 0; by < 4; ++by) {
        const int e = w * 4 + by;
        int q = (int)rintf(Wo[(wave * 64 + l4 * 16 + e) * 16 + l15] * 16384.0f);
        b |= (q & 255) << (8 * by);
      }
      wd[w] = b;
    }
    *reinterpret_cast<i32x4*>(wofs + wave * 1024 + lane * 16) =
        (i32x4){wd[0], wd[1], wd[2], wd[3]};
  }
  const float bh128 = 128.0f * bhn[wave * 16 + l15];
  const float bov = bo[l15];

  const int wrbase = (wave >> 2) * 1024 + ((wave & 3) * 16 + l4 * 4) * 16 + l15;

  float hcur[4];
#pragma unroll
  for (int j = 0; j < 4; ++j) {
    float h = carry0[(size_t)(r0 + l4 * 4 + j) * 256 + wave * 16 + l15];
    hcur[j] = h;
    float m = fmaf(h, 127.0f, FMAGIC);
    int hq = __builtin_bit_cast(int, m) - IMAGIC;
    ha[wrbase + j * 16] = (char)hq;
  }
  __syncthreads();

  const f16* gp0 = gxL + (((size_t)blockIdx.x * 8 + (wave >> 1)) * 6 +
                          (size_t)(wave & 1)) * 256 + (size_t)lane * 4;

  auto head_tau = [&](int tau) {
    const int sbase = (tau & 7) * 4096;
    i32x4 aco = {};
#pragma unroll
    for (int kt = 0; kt < 4; ++kt) {
      i32x4 ah = *reinterpret_cast<const i32x4*>(ha + sbase + kt * 1024 + lane * 16);
      i32x4 wb = *reinterpret_cast<const i32x4*>(wofs + kt * 1024 + lane * 16);
      aco = __builtin_amdgcn_mfma_i32_16x16x64_i8(ah, wb, aco, 0, 0, 0);
    }
#pragma unroll
    for (int r = 0; r < 4; ++r) {
      float y = fmaf((float)aco[r], CHEAD, bov);
      if (l15 >= 8) y = __expf(fminf(fmaxf(y, -20.0f), 2.0f));
      out[((size_t)(tau - 1) * 256 + r0 + l4 * 4 + r) * 16 + l15] = y;
    }
  };

  f16x4 gva[3], gvb[3];
#pragma unroll
  for (int g = 0; g < 3; ++g)
    gva[g] = *reinterpret_cast<const f16x4*>(gp0 + g * 512);

  auto step = [&](int cur, int nxt, f16x4 (&gv)[3], f16x4 (&gvn)[3],
                  const f16* gpn, int tt) {
    if ((tt & 7) == 0 && tt > 0) {
      if (wave < 8) head_tau(tt - 7 + wave);
      asm volatile("s_waitcnt lgkmcnt(0)\n\ts_barrier" ::: "memory");
    }
#pragma unroll
    for (int g = 0; g < 3; ++g)
      gvn[g] = *reinterpret_cast<const f16x4*>(gpn + g * 512);

    i32x4 acc0 = {}, acc1 = {}, acc2 = {};
#pragma unroll
    for (int kt = 0; kt < 4; ++kt) {
      i32x4 a = *reinterpret_cast<const i32x4*>(ha + cur + kt * 1024 + lane * 16);
      acc0 = __builtin_amdgcn_mfma_i32_16x16x64_i8(a, whq[0][kt], acc0, 0, 0, 0);
      acc1 = __builtin_amdgcn_mfma_i32_16x16x64_i8(a, whq[1][kt], acc1, 0, 0, 0);
      acc2 = __builtin_amdgcn_mfma_i32_16x16x64_i8(a, whq[2][kt], acc2, 0, 0, 0);
    }

#pragma unroll
    for (int j = 0; j < 4; ++j) {
      float pr = fmaf((float)acc0[j], CS, (float)gv[0][j]);
      float pz = fmaf((float)acc1[j], CS, (float)gv[1][j]);
      float pnh = fmaf((float)acc2[j], CS, bh128);
      float rg = sigm_s(pr);
      float zg = sigm_s(pz);
      float ng = tanh_s(fmaf(rg, pnh, (float)gv[2][j]));
      float h = ng + zg * (hcur[j] - ng);
      hcur[j] = h;
      float m = fmaf(h, 127.0f, FMAGIC);
      int hq = __builtin_bit_cast(int, m) - IMAGIC;
      ha[nxt + wrbase + j * 16] = (char)hq;
    }
    asm volatile("s_waitcnt lgkmcnt(0)\n\ts_barrier" ::: "memory");
  };

  for (int t = 0; t < 512; t += 2) {
    const f16* gp1 = gp0 + (size_t)(t + 1) * 196608;
    const f16* gp2 = gp0 + (size_t)(t + 2 <= 511 ? t + 2 : 511) * 196608;
    step((t & 7) * 4096, ((t + 1) & 7) * 4096, gva, gvb, gp1, t);
    step(((t + 1) & 7) * 4096, ((t + 2) & 7) * 4096, gvb, gva, gp2, t + 1);
  }

  if (wave < 8) head_tau(505 + wave);
}

extern "C" void kernel_launch(void* const* d_in, const int* in_sizes, int n_in,
                              void* d_out, int out_size, void* d_ws, size_t ws_size,
                              hipStream_t stream) {
  const float* x      = (const float*)d_in[0];
  const float* carry0 = (const float*)d_in[1];
  const float* Wi     = (const float*)d_in[2];
  const float* bi     = (const float*)d_in[3];
  const float* Wh     = (const float*)d_in[4];
  const float* bhn    = (const float*)d_in[5];
  const float* Wo     = (const float*)d_in[6];
  const float* bo     = (const float*)d_in[7];
  float* out = (float*)d_out;

  f16* gx  = (f16*)d_ws;                        // 512*256*768 f16 = 192 MiB
  f16* WiT = gx + (size_t)512 * 256 * 768;      // 768*256 f16 = 384 KiB
  f16* xh  = WiT + (size_t)768 * 256;           // 512*256*256 f16 = 64 MiB

  const size_t need = ((size_t)512 * 256 * 768 + (size_t)768 * 256 +
                       (size_t)512 * 256 * 256) * sizeof(f16);

  k_prep_wit<<<dim3(24, 8), dim3(32, 8), 0, stream>>>(Wi, WiT);
  if (ws_size >= need) {
    k_x16<<<dim3(2048), dim3(256), 0, stream>>>(x, xh);
    k_gemm_gx16<<<dim3(6, 1024), dim3(256), 0, stream>>>(xh, WiT, bi, gx);
  } else {
    k_gemm_gx<<<dim3(6, 1024), dim3(256), 0, stream>>>(x, WiT, bi, gx);
  }
  k_scan<<<dim3(16), dim3(1024), 0, stream>>>(carry0, Wh, bhn, gx, Wo, bo, out);
}